// Round 3
// baseline (71.442 us; speedup 1.0000x reference)
//
#include <hip/hip_runtime.h>
#include <hip/hip_bf16.h>

// QuantizedLinear: out[t][o] = scale[o]*(sum_k x[t][k]*q[o][k] - zp[o]*sum_k x[t][k]) + bias[o]
// T=8, K=4096, OUT=11008. Weights int32 (int8-valued): 180.4 MB streamed once -> memory-bound.
// Roofline: 181 MB @ ~7 TB/s (measured fill BW) ~= 26 us. R2 was 43.3 us at 2 waves/SIMD
// (VGPR-bound). R3: low-register lane layout for 8 waves/SIMD.
//
// Lane layout: lane = (t = lane&7 token, s = lane>>3 k-subsegment).
//   Per iter the wave covers 8 channels x 32 k. Lane loads ONE float4 of x
//   (x[t][k0..k0+3]) and 8 int4 of q (channel c, k0..k0+3). Lanes with equal s
//   share q addresses -> HW broadcast; per q-instr the wave fetches 128 B
//   contiguous. acc[8] = 8 channels x 1 token -> ~56 live VGPRs -> 8 waves/SIMD.
// Reduction: 3-stage halving butterfly over s (21 shfl+add) leaves lane (t,s)
//   holding output (t, c=s). Waves 1..3 spill to LDS; wave 0 combines + stores.
// Grid: 11008/8 = 1376 blocks x 4 waves (split-K=4).

constexpr int K_IN  = 4096;
constexpr int N_OUT = 11008;
constexpr int KQ    = K_IN / 4;      // 1024 k per wave (split-K=4)
constexpr int ITERS = KQ / 32;       // 32 iters of 32 k

__global__ __launch_bounds__(256, 8) void qlin_kernel(
    const float* __restrict__ x,
    const int*   __restrict__ q,
    const float* __restrict__ scale,
    const int*   __restrict__ zp,
    const float* __restrict__ bias,
    float*       __restrict__ out)
{
    __shared__ float partial[3][64];

    const int tid  = threadIdx.x;
    const int lane = tid & 63;
    const int w    = tid >> 6;       // wave = K-quarter 0..3
    const int t    = lane & 7;       // token
    const int s    = lane >> 3;      // k-subsegment 0..7
    const int obase = blockIdx.x * 8;
    const int kbase = w * KQ;

    // Uniform per-channel row pointers -> SGPR saddr; per-lane part is k only.
    const float* xrow = x + t * K_IN;

    float acc[8];
    #pragma unroll
    for (int c = 0; c < 8; ++c) acc[c] = 0.0f;
    float xs = 0.0f;

    for (int it = 0; it < ITERS; ++it) {
        const int k0 = kbase + it * 32 + s * 4;

        const float4 xv = *reinterpret_cast<const float4*>(&xrow[k0]);

        int4 qv[8];
        #pragma unroll
        for (int c = 0; c < 8; ++c)
            qv[c] = *reinterpret_cast<const int4*>(&q[(obase + c) * K_IN + k0]);

        #pragma unroll
        for (int c = 0; c < 8; ++c) {
            acc[c] += xv.x * (float)qv[c].x + xv.y * (float)qv[c].y
                    + xv.z * (float)qv[c].z + xv.w * (float)qv[c].w;
        }
        xs += xv.x + xv.y + xv.z + xv.w;
    }

    // Halving butterfly over s (lane bits 5..3): 8 values -> lane keeps c = s.
    #pragma unroll
    for (int st = 0; st < 3; ++st) {
        const int m    = 32 >> st;
        const int half = 4 >> st;
        const bool hi  = (lane & m) != 0;
        #pragma unroll
        for (int i = 0; i < half; ++i) {
            const float a = acc[i];
            const float b = acc[i + half];
            const float send = hi ? a : b;
            const float recv = __shfl_xor(send, m, 64);
            acc[i] = (hi ? b : a) + recv;
        }
    }

    // Per-token x sum over this wave's K-quarter: reduce over s (all lanes get it).
    #pragma unroll
    for (int m = 8; m <= 32; m <<= 1)
        xs += __shfl_xor(xs, m, 64);

    const int o = obase + s;
    const float v = acc[0] - (float)zp[o] * xs;

    if (w != 0)
        partial[w - 1][lane] = v;
    __syncthreads();
    if (w == 0) {
        const float total = v + partial[0][lane] + partial[1][lane] + partial[2][lane];
        out[t * N_OUT + o] = scale[o] * total + bias[o];
    }
}

extern "C" void kernel_launch(void* const* d_in, const int* in_sizes, int n_in,
                              void* d_out, int out_size, void* d_ws, size_t ws_size,
                              hipStream_t stream) {
    const float* x     = (const float*)d_in[0];
    const int*   q     = (const int*)  d_in[1];
    const float* scale = (const float*)d_in[2];
    const int*   zp    = (const int*)  d_in[3];
    const float* bias  = (const float*)d_in[4];
    float* out = (float*)d_out;

    const int blocks = N_OUT / 8;  // 1376
    qlin_kernel<<<blocks, 256, 0, stream>>>(x, q, scale, zp, bias, out);
}

// Round 5
// 46.220 us; speedup vs baseline: 1.5457x; 1.5457x over previous
//
#include <hip/hip_runtime.h>
#include <hip/hip_bf16.h>

// QuantizedLinear: out[t][o] = scale[o]*(sum_k x[t][k]*q[o][k] - zp[o]*sum_k x[t][k]) + bias[o]
// T=8, K=4096, OUT=11008. Weights int32 (int8-valued): 180.4 MB unique -> memory-bound.
// Roofline: ~26 us at the 7 TB/s the fill kernels demonstrate.
//
// R5 = R4 + butterfly fix. R4's 5-stage reduce used masks {32,16,8,4,2}: lane
// bit 0 never exchanged -> even lanes summed only even lanes (absmax ~ half
// magnitude). Fix: final mask-1 exchange makes lane pairs true duplicates.
//
// Structure: block = 256 = 4 waves; wave w: token-half th=w&1 (4 tokens),
//   channel-group cg=w>>1 (8 channels), FULL K=4096 (16 iters x 256 k).
//   No split-K, no LDS, no syncthreads.
//   Per iter per lane: 4 float4 x-loads + 8 int4 q-loads (fully coalesced,
//   1024 B/instr, 12 independent loads in flight). acc[32] = 4t x 8c.
//   ~104 VGPRs -> 4 waves/SIMD via __launch_bounds__(256,4).
//   Twin token-half waves read identical q streams -> L1/L2 dedup, HBM unchanged.
// Grid: 11008/16 = 688 blocks = 2752 waves -> fully co-resident, no tail.

constexpr int K_IN  = 4096;
constexpr int N_OUT = 11008;
constexpr int ITERS = K_IN / 256;    // 16

__global__ __launch_bounds__(256, 4) void qlin_kernel(
    const float* __restrict__ x,
    const int*   __restrict__ q,
    const float* __restrict__ scale,
    const int*   __restrict__ zp,
    const float* __restrict__ bias,
    float*       __restrict__ out)
{
    const int tid  = threadIdx.x;
    const int lane = tid & 63;
    const int w    = tid >> 6;
    const int th   = w & 1;          // token half: tokens th*4 .. th*4+3
    const int cg   = w >> 1;         // channel group within block
    const int obase = blockIdx.x * 16 + cg * 8;
    const int tbase = th * 4;

    float acc[32];
    #pragma unroll
    for (int i = 0; i < 32; ++i) acc[i] = 0.0f;
    float xs[4] = {0.0f, 0.0f, 0.0f, 0.0f};

    #pragma unroll 2
    for (int it = 0; it < ITERS; ++it) {
        const int k0 = it * 256 + lane * 4;

        float4 xv[4];
        #pragma unroll
        for (int t = 0; t < 4; ++t)
            xv[t] = *reinterpret_cast<const float4*>(&x[(tbase + t) * K_IN + k0]);

        int4 qv[8];
        #pragma unroll
        for (int c = 0; c < 8; ++c)
            qv[c] = *reinterpret_cast<const int4*>(&q[(obase + c) * K_IN + k0]);

        #pragma unroll
        for (int c = 0; c < 8; ++c) {
            const float q0 = (float)qv[c].x;
            const float q1 = (float)qv[c].y;
            const float q2 = (float)qv[c].z;
            const float q3 = (float)qv[c].w;
            #pragma unroll
            for (int t = 0; t < 4; ++t) {
                acc[t * 8 + c] += xv[t].x * q0 + xv[t].y * q1
                                + xv[t].z * q2 + xv[t].w * q3;
            }
        }
        #pragma unroll
        for (int t = 0; t < 4; ++t)
            xs[t] += xv[t].x + xv[t].y + xv[t].z + xv[t].w;
    }

    // Halving butterfly over lane bits 5..1: 32 partials -> lane l holds value
    // j=l>>1, summed over lanes of matching parity.
    #pragma unroll
    for (int st = 0; st < 5; ++st) {
        const int m    = 32 >> st;
        const int half = 16 >> st;
        const bool hi  = (lane & m) != 0;
        #pragma unroll
        for (int i = 0; i < half; ++i) {
            const float a = acc[i];
            const float b = acc[i + half];
            const float send = hi ? a : b;
            const float recv = __shfl_xor(send, m, 64);
            acc[i] = (hi ? b : a) + recv;
        }
    }
    // Final mask-1 exchange: combine even-lane and odd-lane partial sums.
    acc[0] += __shfl_xor(acc[0], 1, 64);

    // Per-token x sums over full K (all lanes get all 4).
    #pragma unroll
    for (int m = 1; m <= 32; m <<= 1) {
        #pragma unroll
        for (int t = 0; t < 4; ++t)
            xs[t] += __shfl_xor(xs[t], m, 64);
    }

    const int j  = lane >> 1;
    const int tl = j >> 3;           // local token 0..3
    const int c  = j & 7;
    const int o  = obase + c;
    if ((lane & 1) == 0) {
        const float total = acc[0] - (float)zp[o] * xs[tl];
        out[(tbase + tl) * N_OUT + o] = scale[o] * total + bias[o];
    }
}

extern "C" void kernel_launch(void* const* d_in, const int* in_sizes, int n_in,
                              void* d_out, int out_size, void* d_ws, size_t ws_size,
                              hipStream_t stream) {
    const float* x     = (const float*)d_in[0];
    const int*   q     = (const int*)  d_in[1];
    const float* scale = (const float*)d_in[2];
    const int*   zp    = (const int*)  d_in[3];
    const float* bias  = (const float*)d_in[4];
    float* out = (float*)d_out;

    const int blocks = N_OUT / 16;  // 688
    qlin_kernel<<<blocks, 256, 0, stream>>>(x, q, scale, zp, bias, out);
}

// Round 6
// 45.002 us; speedup vs baseline: 1.5875x; 1.0271x over previous
//
#include <hip/hip_runtime.h>
#include <hip/hip_bf16.h>

// QuantizedLinear: out[t][o] = scale[o]*(sum_k x[t][k]*q[o][k] - zp[o]*sum_k x[t][k]) + bias[o]
// T=8, K=4096, OUT=11008. Weights int32 (int8-valued): 180.4 MB unique -> memory-bound.
// Roofline: ~26-29 us at fill-demonstrated ~7 TB/s (less if L3-resident half holds).
//
// R6: max wave count + low VGPR + co-located token twins.
//   Ladder: R1 49.0us (2752 waves) / R2 43.3 (5504) / R5 46.2 (2752, acc32).
//   Wave count is the lever -> 11008 waves (10.75/SIMD of work).
//   block = 512 threads = 8 waves: th = w&1 (4 tokens), kq = w>>1 (K-quarter, 1024 k).
//   Wave: 8 ch x 4 tok x 1024 k = 4 iters of 256 k.
//   Per iter per lane: 4 float4 x + 8 int4 q loads (1024 B/instr, 12 in flight).
//   acc[32] (4t x 8c) -> ~100 VGPR -> 4 waves/SIMD via __launch_bounds__(512,4).
//   Twin th-waves share q stream IN THE SAME BLOCK -> L1 hit on second read.
//   Cross-kq combine via 1.5 KB LDS; kq=0 waves apply scale/zp/bias and store.
// Grid: 11008/8 = 1376 blocks.

constexpr int K_IN  = 4096;
constexpr int N_OUT = 11008;
constexpr int KQ    = K_IN / 4;      // 1024 k per wave
constexpr int ITERS = KQ / 256;      // 4

__global__ __launch_bounds__(512, 4) void qlin_kernel(
    const float* __restrict__ x,
    const int*   __restrict__ q,
    const float* __restrict__ scale,
    const int*   __restrict__ zp,
    const float* __restrict__ bias,
    float*       __restrict__ out)
{
    __shared__ float partial[3][2][64];

    const int tid  = threadIdx.x;
    const int lane = tid & 63;
    const int w    = tid >> 6;       // 0..7
    const int th   = w & 1;          // token half
    const int kq   = w >> 1;         // K-quarter
    const int obase = blockIdx.x * 8;
    const int tbase = th * 4;
    const int kbase = kq * KQ;

    float acc[32];
    #pragma unroll
    for (int i = 0; i < 32; ++i) acc[i] = 0.0f;
    float xs[4] = {0.0f, 0.0f, 0.0f, 0.0f};

    #pragma unroll 2
    for (int it = 0; it < ITERS; ++it) {
        const int k0 = kbase + it * 256 + lane * 4;

        float4 xv[4];
        #pragma unroll
        for (int t = 0; t < 4; ++t)
            xv[t] = *reinterpret_cast<const float4*>(&x[(tbase + t) * K_IN + k0]);

        int4 qv[8];
        #pragma unroll
        for (int c = 0; c < 8; ++c)
            qv[c] = *reinterpret_cast<const int4*>(&q[(obase + c) * K_IN + k0]);

        #pragma unroll
        for (int c = 0; c < 8; ++c) {
            const float q0 = (float)qv[c].x;
            const float q1 = (float)qv[c].y;
            const float q2 = (float)qv[c].z;
            const float q3 = (float)qv[c].w;
            #pragma unroll
            for (int t = 0; t < 4; ++t) {
                acc[t * 8 + c] += xv[t].x * q0 + xv[t].y * q1
                                + xv[t].z * q2 + xv[t].w * q3;
            }
        }
        #pragma unroll
        for (int t = 0; t < 4; ++t)
            xs[t] += xv[t].x + xv[t].y + xv[t].z + xv[t].w;
    }

    // Halving butterfly over lane bits 5..1 (verified in R5): 32 partials ->
    // lane l holds value j=l>>1 summed over same-parity lanes; mask-1 exchange
    // then merges parities so lane pairs hold the true sum.
    #pragma unroll
    for (int st = 0; st < 5; ++st) {
        const int m    = 32 >> st;
        const int half = 16 >> st;
        const bool hi  = (lane & m) != 0;
        #pragma unroll
        for (int i = 0; i < half; ++i) {
            const float a = acc[i];
            const float b = acc[i + half];
            const float send = hi ? a : b;
            const float recv = __shfl_xor(send, m, 64);
            acc[i] = (hi ? b : a) + recv;
        }
    }
    acc[0] += __shfl_xor(acc[0], 1, 64);

    // Per-token x sums over this wave's K-quarter (all lanes get all 4).
    #pragma unroll
    for (int m = 1; m <= 32; m <<= 1) {
        #pragma unroll
        for (int t = 0; t < 4; ++t)
            xs[t] += __shfl_xor(xs[t], m, 64);
    }

    const int j  = lane >> 1;
    const int tl = j >> 3;           // local token 0..3
    const int c  = j & 7;
    const int o  = obase + c;
    const float v = acc[0] - (float)zp[o] * xs[tl];  // this wave's K-quarter contribution

    if (kq != 0)
        partial[kq - 1][th][lane] = v;
    __syncthreads();
    if (kq == 0 && (lane & 1) == 0) {
        const float total = v + partial[0][th][lane]
                              + partial[1][th][lane]
                              + partial[2][th][lane];
        out[(tbase + tl) * N_OUT + o] = scale[o] * total + bias[o];
    }
}

extern "C" void kernel_launch(void* const* d_in, const int* in_sizes, int n_in,
                              void* d_out, int out_size, void* d_ws, size_t ws_size,
                              hipStream_t stream) {
    const float* x     = (const float*)d_in[0];
    const int*   q     = (const int*)  d_in[1];
    const float* scale = (const float*)d_in[2];
    const int*   zp    = (const int*)  d_in[3];
    const float* bias  = (const float*)d_in[4];
    float* out = (float*)d_out;

    const int blocks = N_OUT / 8;  // 1376
    qlin_kernel<<<blocks, 512, 0, stream>>>(x, q, scale, zp, bias, out);
}